// Round 1
// baseline (168.633 us; speedup 1.0000x reference)
//
#include <hip/hip_runtime.h>

// GRU fused, MI355X/gfx950 — round 3.
// Key changes vs r2:
//  * 8 waves x 16 cols (512 thr) instead of 4 waves x 32 cols: weight regs
//    120 -> 60 VGPR/wave, so total regs fit 128 -> 4 waves/SIMD.
//  * MB 32 -> 16, grid 512 -> 1024: 2 blocks/CU x 8 waves = 16 waves/CU (2x occ),
//    and the two resident blocks desync across the per-step barrier.
//  * lh double-buffered -> ONE __syncthreads per step (was 2): write h_{t+1}
//    into the alternate buffer, WAR hazard gone.
//  * loop-invariant bias scalars hoisted out of the t-loop.

#define B_  16384
#define T_  28
#define F_  28
#define H_  128
#define C_  10
#define MB  16     // batch rows per block
#define LHS 136    // lh row stride in ushorts (272 B: 16B-aligned, dword-stride 68 == 4 mod 32 -> 2-way = free)
#define LXS 40     // lx row stride in ushorts (80 B)

typedef short  short8  __attribute__((ext_vector_type(8)));
typedef short  short4v __attribute__((ext_vector_type(4)));
typedef float  f32x4   __attribute__((ext_vector_type(4)));

__device__ __forceinline__ unsigned short f2bf(float f) {   // RNE fp32->bf16
    unsigned u = __builtin_bit_cast(unsigned, f);
    u += 0x7fffu + ((u >> 16) & 1u);
    return (unsigned short)(u >> 16);
}
__device__ __forceinline__ float bf2f(unsigned short h) {
    unsigned u = ((unsigned)h) << 16;
    return __builtin_bit_cast(float, u);
}
__device__ __forceinline__ float fast_sig(float x) {        // 1/(1+e^-x)
    float e = __builtin_amdgcn_exp2f(x * -1.442695040888963f);
    return __builtin_amdgcn_rcpf(1.0f + e);
}
__device__ __forceinline__ float fast_tanh(float x) {       // 1 - 2/(1+e^{2x})
    float e = __builtin_amdgcn_exp2f(x * 2.885390081777927f);
    return 1.0f - 2.0f * __builtin_amdgcn_rcpf(1.0f + e);
}

__global__ __launch_bounds__(512, 4)
void gru_fused(const float* __restrict__ x,     // (B,T,F)
               const float* __restrict__ wk,    // (F,3H) = (28,384)
               const float* __restrict__ wrk,   // (H,3H) = (128,384)
               const float* __restrict__ bias,  // (2,3H)
               const float* __restrict__ dw,    // (H,C)
               const float* __restrict__ db,    // (C,)
               float* __restrict__ out)         // (B,C)
{
    // ---- LDS (~19 KB) ----
    __shared__ __align__(16) unsigned short lh[2][MB*LHS];  // h bf16, double-buffered
    __shared__ __align__(16) unsigned short lx[2][MB*LXS];  // x_t bf16 staging, double-buffered
    __shared__ float lbias[512];   // [0..255]=bi+br (z,r), [256..383]=bi_h, [384..511]=br_h
    __shared__ float ldw[H_*C_];
    __shared__ float ldb[16];
    __shared__ float llog[MB][C_];

    const int tid  = threadIdx.x;
    const int base = blockIdx.x * MB;
    const int lane = tid & 63;
    const int wc   = tid >> 6;    // wave id 0..7 -> 16-column slice
    const int n    = lane & 15;   // MFMA: A row / D col
    const int q    = lane >> 4;   // MFMA quad

    // ---- loop-invariant weight fragments -> REGISTERS (60 VGPR/wave) ----
    // B-frag layout (verified r1): elem(lane,j) = W[k = kb*32 + q*8 + j][col], col = wc*16 + n
    short8 wzr[4], wrr[4], whr[4];   // W_rec per kb, gates z/r/h: 48 VGPR
    short8 xzr, xrr, xhr;            // kernel (K pad 28->32): 12 VGPR
    const int col = wc*16 + n;
    {
        #pragma unroll
        for (int kb = 0; kb < 4; ++kb) {
            const int k0 = kb*32 + q*8;
            short8 vz, vr, vh;
            #pragma unroll
            for (int j = 0; j < 8; ++j) {
                const float* wp = wrk + (size_t)(k0 + j)*384 + col;
                vz[j] = (short)f2bf(wp[0]);
                vr[j] = (short)f2bf(wp[128]);
                vh[j] = (short)f2bf(wp[256]);
            }
            wzr[kb] = vz; wrr[kb] = vr; whr[kb] = vh;
        }
        short8 vz, vr, vh;
        #pragma unroll
        for (int j = 0; j < 8; ++j) {
            const int k = q*8 + j;
            if (k < F_) {
                const float* wp = wk + (size_t)k*384 + col;
                vz[j] = (short)f2bf(wp[0]);
                vr[j] = (short)f2bf(wp[128]);
                vh[j] = (short)f2bf(wp[256]);
            } else { vz[j] = 0; vr[j] = 0; vh[j] = 0; }
        }
        xzr = vz; xrr = vr; xhr = vh;
    }

    // ---- biases / dense weights / h0 / x0 ----
    if (tid < 256)      lbias[tid] = bias[tid] + bias[384 + tid];   // z,r combined
    else if (tid < 384) lbias[tid] = bias[tid];                     // bi_h
    else                lbias[tid] = bias[tid + 256];               // br_h
    for (int i = tid; i < H_*C_; i += 512) ldw[i] = dw[i];
    if (tid < C_) ldb[tid] = db[tid];
    for (int i = tid; i < MB*LHS/2; i += 512) ((unsigned*)lh[0])[i] = 0u;
    {
        const int row = tid >> 5, seg = tid & 31;
        if (seg < 8) {
            short4v v = (short4v){0,0,0,0};
            if (seg < 7) {
                float4 a = *(const float4*)(x + (size_t)(base + row)*(T_*F_) + seg*4);
                v[0]=(short)f2bf(a.x); v[1]=(short)f2bf(a.y); v[2]=(short)f2bf(a.z); v[3]=(short)f2bf(a.w);
            }
            *(short4v*)&lx[0][row*LXS + seg*4] = v;
        }
    }

    __syncthreads();   // init visible

    // loop-invariant bias scalars (4 VGPR)
    const float bz = lbias[col], brr = lbias[128 + col];
    const float bx = lbias[256 + col], bh = lbias[384 + col];

    float hm[4];                  // fp32 h master, D-layout rows q*4+reg
    hm[0]=0.f; hm[1]=0.f; hm[2]=0.f; hm[3]=0.f;

    for (int t = 0; t < T_; ++t) {
        const unsigned short* __restrict__ lhr = lh[t & 1];
        unsigned short* __restrict__ lhw = lh[(t + 1) & 1];

        // global prefetch of x_{t+1} (issue early; latency hides under MFMA+gates)
        float4 pa = make_float4(0.f,0.f,0.f,0.f);
        const int prow = tid >> 5, pseg = tid & 31;
        const bool pn = (t + 1 < T_);
        if (pn && pseg < 7)
            pa = *(const float4*)(x + (size_t)(base + prow)*(T_*F_) + (t+1)*F_ + pseg*4);

        // A-fragments (same rows for all 8 waves): A[m=n][k=kb*32+q*8+j]
        short8 ha[4], xav;
        {
            const int rbase = n*LHS;
            #pragma unroll
            for (int kb = 0; kb < 4; ++kb)
                ha[kb] = *(const short8*)&lhr[rbase + kb*32 + q*8];
            xav = *(const short8*)&lx[t & 1][n*LXS + q*8];
        }

        f32x4 az = (f32x4){bz,bz,bz,bz};
        f32x4 ar = (f32x4){brr,brr,brr,brr};
        f32x4 ax = (f32x4){bx,bx,bx,bx};
        f32x4 ah = (f32x4){bh,bh,bh,bh};
        #pragma unroll
        for (int kb = 0; kb < 4; ++kb) {
            az = __builtin_amdgcn_mfma_f32_16x16x32_bf16(ha[kb], wzr[kb], az, 0,0,0);
            ar = __builtin_amdgcn_mfma_f32_16x16x32_bf16(ha[kb], wrr[kb], ar, 0,0,0);
            ah = __builtin_amdgcn_mfma_f32_16x16x32_bf16(ha[kb], whr[kb], ah, 0,0,0);
        }
        az = __builtin_amdgcn_mfma_f32_16x16x32_bf16(xav, xzr, az, 0,0,0);
        ar = __builtin_amdgcn_mfma_f32_16x16x32_bf16(xav, xrr, ar, 0,0,0);
        ax = __builtin_amdgcn_mfma_f32_16x16x32_bf16(xav, xhr, ax, 0,0,0);

        // gates + h update; D layout: row = q*4+reg (batch), col = n (-> feature col)
        #pragma unroll
        for (int reg = 0; reg < 4; ++reg) {
            float z  = fast_sig(az[reg]);
            float r  = fast_sig(ar[reg]);
            float hh = fast_tanh(ax[reg] + r * ah[reg]);
            float hp = hm[reg];
            float hn = hh + z * (hp - hh);
            hm[reg] = hn;
            lhw[(q*4 + reg)*LHS + col] = f2bf(hn);
        }

        // commit prefetched x into the other parity buffer
        if (pn && pseg < 8) {
            short4v v = (short4v){0,0,0,0};
            if (pseg < 7) {
                v[0]=(short)f2bf(pa.x); v[1]=(short)f2bf(pa.y);
                v[2]=(short)f2bf(pa.z); v[3]=(short)f2bf(pa.w);
            }
            *(short4v*)&lx[(t+1) & 1][prow*LXS + pseg*4] = v;
        }

        __syncthreads();   // h_{t+1}/x_{t+1} published; next step may read
    }

    // ---- dense + softmax epilogue (final h is in lh[0]: last write was t=27 -> (27+1)&1) ----
    if (tid < MB*C_) {
        const int row = tid / C_, c = tid - row*C_;
        float s = ldb[c];
        #pragma unroll
        for (int u0 = 0; u0 < H_; u0 += 8) {
            short8 hv = *(const short8*)&lh[0][row*LHS + u0];
            #pragma unroll
            for (int j = 0; j < 8; ++j)
                s += bf2f((unsigned short)hv[j]) * ldw[(u0+j)*C_ + c];
        }
        llog[row][c] = s;
    }
    __syncthreads();
    if (tid < MB) {
        const int row = tid;
        float m = llog[row][0];
        #pragma unroll
        for (int c = 1; c < C_; ++c) m = fmaxf(m, llog[row][c]);
        float e[C_], s = 0.f;
        #pragma unroll
        for (int c = 0; c < C_; ++c) {
            e[c] = __builtin_amdgcn_exp2f((llog[row][c] - m) * 1.442695040888963f);
            s += e[c];
        }
        const float inv = __builtin_amdgcn_rcpf(s);
        float* o = out + (size_t)(base + row)*C_;
        #pragma unroll
        for (int c = 0; c < C_; ++c) o[c] = e[c] * inv;
    }
}

extern "C" void kernel_launch(void* const* d_in, const int* in_sizes, int n_in,
                              void* d_out, int out_size, void* d_ws, size_t ws_size,
                              hipStream_t stream) {
    const float* x   = (const float*)d_in[0];
    const float* wk  = (const float*)d_in[1];
    const float* wrk = (const float*)d_in[2];
    const float* bs  = (const float*)d_in[3];
    const float* dw  = (const float*)d_in[4];
    const float* db  = (const float*)d_in[5];
    (void)in_sizes; (void)n_in; (void)out_size; (void)d_ws; (void)ws_size;
    gru_fused<<<dim3(B_/MB), dim3(512), 0, stream>>>(x, wk, wrk, bs, dw, db, (float*)d_out);
}